// Round 6
// baseline (137.666 us; speedup 1.0000x reference)
//
#include <hip/hip_runtime.h>

#define S_LEN 2048
#define HEADS 16
#define DIM 64

typedef __attribute__((ext_vector_type(8))) short short8;
typedef __attribute__((ext_vector_type(16))) float float16v;
typedef __attribute__((ext_vector_type(4))) float float4v;
typedef __attribute__((ext_vector_type(4))) unsigned uint4v;

// packed fp32x2 -> bf16x2 (RNE), lo = first arg
static __device__ __forceinline__ unsigned pkbf(float lo, float hi) {
  unsigned r;
  asm("v_cvt_pk_bf16_f32 %0, %1, %2" : "=v"(r) : "v"(lo), "v"(hi));
  return r;
}

// async global->LDS, 16B per lane; LDS dest = wave-uniform base + lane*16
static __device__ __forceinline__ void gll16(const short* g, short* l) {
  __builtin_amdgcn_global_load_lds(
      (const __attribute__((address_space(1))) void*)g,
      (__attribute__((address_space(3))) void*)l, 16, 0, 0);
}

// raw workgroup barrier with compiler memory fence (no implicit vmcnt drain)
static __device__ __forceinline__ void bar() {
  asm volatile("" ::: "memory");
  __builtin_amdgcn_s_barrier();
  asm volatile("" ::: "memory");
}

// ---------------- prep ----------------
// K: fp32 [bh][j][f] -> bf16, stored in MFMA-A-fragment order per 32-key tile:
//    kb[bh][jt][ks][hf][n][e]  (shorts: jt*2048 + ks*512 + hf*256 + n*8 + e)
//    holding K[jt*32+n][16ks+8hf+e] -- a tile is 4 contiguous 1KB chunks.
// V: fp32 [bh][j][f] -> bf16 V^T with bit2<->3 j-permute (matches P^T register
//    layout), stored fragment-ordered per 32-key tile:
//    vt[bh][jt][q=fh*2+kc][hf][n][e] holding V^T[f=fh*32+n][p=kc*16+8hf+e]
__global__ __launch_bounds__(256) void prep(const float* __restrict__ kk,
                                            const float* __restrict__ vv,
                                            short* __restrict__ kb,
                                            short* __restrict__ vt) {
  __shared__ unsigned t32[64 * 33];  // [f][p2] u32 = bf16 pair (p even, p odd)
  const int bx = blockIdx.x;
  const int bh = bx >> 5;
  const int j0 = (bx & 31) * 64;
  const int tid = threadIdx.x;

  // K convert -> fragment-ordered
  {
    const int j = tid >> 2, f0 = (tid & 3) * 16;
    const float4v* src = (const float4v*)(kk + ((size_t)bh * S_LEN + j0 + j) * DIM + f0);
    float4v a0 = src[0], a1 = src[1], a2 = src[2], a3 = src[3];
    uint4v w0, w1;
    w0[0] = pkbf(a0[0], a0[1]); w0[1] = pkbf(a0[2], a0[3]);
    w0[2] = pkbf(a1[0], a1[1]); w0[3] = pkbf(a1[2], a1[3]);
    w1[0] = pkbf(a2[0], a2[1]); w1[1] = pkbf(a2[2], a2[3]);
    w1[2] = pkbf(a3[0], a3[1]); w1[3] = pkbf(a3[2], a3[3]);
    short* dstb = kb + (size_t)bh * (S_LEN * DIM) +
                  ((j0 >> 5) + (j >> 5)) * 2048 + (f0 >> 4) * 512 + (j & 31) * 8;
    *(uint4v*)dstb = w0;            // hf = 0 chunk (f0..f0+7)
    *(uint4v*)(dstb + 256) = w1;    // hf = 1 chunk (f0+8..f0+15)
  }
  // V transpose + bit2<->3 permute; pack adjacent-j pairs
  {
    const int jp = (tid & 31) * 2, f0 = (tid >> 5) * 8;
    const int pp = ((jp & ~12) | ((jp & 4) << 1) | ((jp & 8) >> 1)) >> 1;
    const float* r0 = vv + ((size_t)bh * S_LEN + j0 + jp) * DIM + f0;
    const float* r1 = r0 + DIM;
    float4v a0 = *(const float4v*)r0, a1 = *(const float4v*)(r0 + 4);
    float4v b0 = *(const float4v*)r1, b1 = *(const float4v*)(r1 + 4);
#pragma unroll
    for (int e = 0; e < 4; e++) {
      t32[(f0 + e) * 33 + pp]     = pkbf(a0[e], b0[e]);
      t32[(f0 + 4 + e) * 33 + pp] = pkbf(a1[e], b1[e]);
    }
  }
  __syncthreads();
  {
    const int f = tid >> 2, x0 = (tid & 3) * 8;
    uint4v c0 = *(const uint4v*)&t32[f * 33 + x0];       // p = 2*x0 .. 2*x0+7  (hf=0)
    uint4v c1 = *(const uint4v*)&t32[f * 33 + x0 + 4];   // p = 2*x0+8 .. +15   (hf=1)
    const int jt = (j0 >> 5) + (x0 >> 4);
    const int qd = (f >> 5) * 2 + ((x0 >> 3) & 1);       // fh*2 + kc
    short* dstb = vt + (size_t)bh * (S_LEN * DIM) + jt * 2048 + qd * 512 + (f & 31) * 8;
    *(uint4v*)dstb = c0;
    *(uint4v*)(dstb + 256) = c1;
  }
}

// ---------------- fused attention: i-split waves, LDS-shared K/V ----------------
// grid 512 = 32 bh * 16 i-blocks(128 rows); block 256 = 4 waves.
// Wave w owns i-rows [it*128 + w*32, +32) and iterates over ALL 2048 keys in
// 64-key tiles. The 4 waves SHARE each K/V tile staged once into LDS via
// global_load_lds (quarters per-CU L2 read traffic vs per-wave direct loads --
// the resource round-5 showed saturated). Double-buffered, counted vmcnt(4)
// (never 0 in-loop), raw s_barrier pair per tile (round-1-verified skeleton).
// i-split makes softmax denom and output fully wave-local: no cross-wave
// epilogue. QK chain split 2+2 to halve MFMA accumulate latency.
__global__ __launch_bounds__(256, 2) void attn_fwd(const float* __restrict__ q,
                                                   const short* __restrict__ kb,
                                                   const short* __restrict__ vt,
                                                   float* __restrict__ out) {
  // 32KB: dbuf 2 x (K 8KB + V 8KB); epilogue reuses first 16.9KB as 4 x [32][33] f32
  __shared__ alignas(16) short lds[16384];
  const int bx0 = blockIdx.x;
  const int bx = (bx0 & 7) * 64 + (bx0 >> 3);  // XCD-chunked swizzle (512%8==0, bijective)
  const int bh = bx >> 4, it = bx & 15;
  const int b = bh >> 4, h = bh & 15;
  const int tid = threadIdx.x;
  const int w = tid >> 6, lane = tid & 63;
  const int n = lane & 31, hf = lane >> 5;
  const int i0 = it * 128 + w * 32;  // this wave's 32 i-rows

  // Q B-frag: lane holds Q[i0+n][f = ks*16 + hf*8 + e], scaled by log2(e)/8
  short8 qa[4];
  {
    const float sc = 0.125f * 1.44269504088896f;
    const float* qr = q + ((size_t)bh * S_LEN + i0 + n) * DIM + hf * 8;
#pragma unroll
    for (int ks = 0; ks < 4; ks++) {
      float4v x0 = *(const float4v*)(qr + ks * 16);
      float4v x1 = *(const float4v*)(qr + ks * 16 + 4);
      uint4v pk_;
      pk_[0] = pkbf(x0[0] * sc, x0[1] * sc); pk_[1] = pkbf(x0[2] * sc, x0[3] * sc);
      pk_[2] = pkbf(x1[0] * sc, x1[1] * sc); pk_[3] = pkbf(x1[2] * sc, x1[3] * sc);
      qa[ks] = *(short8*)&pk_;
    }
  }

  const short* kbase = kb + (size_t)bh * (S_LEN * DIM);
  const short* vbase = vt + (size_t)bh * (S_LEN * DIM);

  float16v zz;
#pragma unroll
  for (int e = 0; e < 16; e++) zz[e] = 0.f;
  float16v a0 = zz, a1 = zz;       // O^T: a0 f=0..31, a1 f=32..63; col i = n
  float lpa = 0.f, lpb = 0.f;      // split softmax-denom partial chains

  // stage one 64-key tile: wave w loads 1KB chunk w of K and V for both 32-key
  // subtiles (4 gll16/wave; 16 total/block). LDS layout == global fragment order.
  auto stage = [&](short* dst, int t) {
    const int jt = 2 * t;
#pragma unroll
    for (int s = 0; s < 2; ++s) {
      gll16(kbase + (size_t)(jt + s) * 2048 + w * 512 + lane * 8, dst + s * 2048 + w * 512);
      gll16(vbase + (size_t)(jt + s) * 2048 + w * 512 + lane * 8, dst + 4096 + s * 2048 + w * 512);
    }
  };

  // one 32-key subtile: QK (2+2 split chains) -> exp2 -> pack -> PV
  auto compute = [&](const short* kl, const short* vl) {
    short8 kf0 = *(const short8*)(kl + lane * 8);
    short8 kf1 = *(const short8*)(kl + 512 + lane * 8);
    short8 kf2 = *(const short8*)(kl + 1024 + lane * 8);
    short8 kf3 = *(const short8*)(kl + 1536 + lane * 8);
    __builtin_amdgcn_s_setprio(1);
    float16v sa = __builtin_amdgcn_mfma_f32_32x32x16_bf16(kf0, qa[0], zz, 0, 0, 0);
    float16v sb = __builtin_amdgcn_mfma_f32_32x32x16_bf16(kf2, qa[2], zz, 0, 0, 0);
    sa = __builtin_amdgcn_mfma_f32_32x32x16_bf16(kf1, qa[1], sa, 0, 0, 0);
    sb = __builtin_amdgcn_mfma_f32_32x32x16_bf16(kf3, qa[3], sb, 0, 0, 0);
    __builtin_amdgcn_s_setprio(0);
    float16v st;
#pragma unroll
    for (int e = 0; e < 16; e++) st[e] = __builtin_amdgcn_exp2f(sa[e] + sb[e]);
#pragma unroll
    for (int e = 0; e < 8; e++) { lpa += st[2 * e]; lpb += st[2 * e + 1]; }
    uint4v pb0, pb1;
#pragma unroll
    for (int u = 0; u < 4; u++) {
      pb0[u] = pkbf(st[2 * u], st[2 * u + 1]);
      pb1[u] = pkbf(st[8 + 2 * u], st[8 + 2 * u + 1]);
    }
    short8 p0 = *(short8*)&pb0, p1 = *(short8*)&pb1;
    short8 vf0 = *(const short8*)(vl + lane * 8);
    short8 vf1 = *(const short8*)(vl + 512 + lane * 8);
    short8 vf2 = *(const short8*)(vl + 1024 + lane * 8);
    short8 vf3 = *(const short8*)(vl + 1536 + lane * 8);
    __builtin_amdgcn_s_setprio(1);
    a0 = __builtin_amdgcn_mfma_f32_32x32x16_bf16(vf0, p0, a0, 0, 0, 0);
    a1 = __builtin_amdgcn_mfma_f32_32x32x16_bf16(vf2, p0, a1, 0, 0, 0);
    a0 = __builtin_amdgcn_mfma_f32_32x32x16_bf16(vf1, p1, a0, 0, 0, 0);
    a1 = __builtin_amdgcn_mfma_f32_32x32x16_bf16(vf3, p1, a1, 0, 0, 0);
    __builtin_amdgcn_s_setprio(0);
  };

  stage(lds, 0);
#pragma unroll 1
  for (int t = 0; t < 32; ++t) {
    short* cur = lds + (t & 1) * 8192;
    if (t < 31) {
      stage(lds + ((t + 1) & 1) * 8192, t + 1);     // next tile's 4 loads in flight
      asm volatile("s_waitcnt vmcnt(4)" ::: "memory");  // this tile's 4 landed
    } else {
      asm volatile("s_waitcnt vmcnt(0)" ::: "memory");
    }
    bar();                      // all waves' chunks for tile t landed
    compute(cur, cur + 4096);                 // subtile A (keys jt=2t)
    compute(cur + 2048, cur + 4096 + 2048);   // subtile B (keys jt=2t+1)
    bar();                      // tile t fully consumed -> safe to restage buffer
  }

  // wave-local softmax denom: lanes n / n+32 hold complementary j-rows of col i=n
  float d = lpa + lpb;
  d += __shfl_xor(d, 32);
  const float inv = 1.f / d;

  // epilogue (fully wave-local; loop's final barrier freed the LDS for all waves)
  float* const tb = (float*)lds + w * 1056;  // own [32][33] f32 slot
  {  // pass 0: f = 0..31 (a0)
#pragma unroll
    for (int c = 0; c < 4; c++) {
      float4v u;
#pragma unroll
      for (int e = 0; e < 4; e++) u[e] = a0[4 * c + e] * inv;
      *(float4v*)&tb[n * 33 + 8 * c + 4 * hf] = u;  // f_local = 8c + 4hf + e
    }
    const int il = lane >> 1, fq = (lane & 1) * 16;
    const float* src = &tb[il * 33 + fq];
    float* dst = out + (((size_t)b * S_LEN + i0 + il) * HEADS + h) * DIM + fq;
#pragma unroll
    for (int u = 0; u < 4; u++) ((float4v*)dst)[u] = ((const float4v*)src)[u];
  }
  {  // pass 1: f = 32..63 (a1); same slot, wave-internal ordering via lgkmcnt
#pragma unroll
    for (int c = 0; c < 4; c++) {
      float4v u;
#pragma unroll
      for (int e = 0; e < 4; e++) u[e] = a1[4 * c + e] * inv;
      *(float4v*)&tb[n * 33 + 8 * c + 4 * hf] = u;
    }
    const int il = lane >> 1, fq = (lane & 1) * 16;
    const float* src = &tb[il * 33 + fq];
    float* dst = out + (((size_t)b * S_LEN + i0 + il) * HEADS + h) * DIM + 32 + fq;
#pragma unroll
    for (int u = 0; u < 4; u++) ((float4v*)dst)[u] = ((const float4v*)src)[u];
  }
}

extern "C" void kernel_launch(void* const* d_in, const int* in_sizes, int n_in,
                              void* d_out, int out_size, void* d_ws, size_t ws_size,
                              hipStream_t stream) {
  const float* q = (const float*)d_in[0];
  const float* k = (const float*)d_in[1];
  const float* v = (const float*)d_in[2];
  float* out = (float*)d_out;
  short* kb = (short*)d_ws;                             // 8 MiB bf16 K (fragment-ordered)
  short* vt = (short*)d_ws + (size_t)32 * S_LEN * DIM;  // 8 MiB bf16 V^T (fragment-ordered)

  prep<<<1024, 256, 0, stream>>>(k, v, kb, vt);
  attn_fwd<<<512, 256, 0, stream>>>(q, kb, vt, out);
}